// Round 6
// baseline (428.147 us; speedup 1.0000x reference)
//
#include <hip/hip_runtime.h>
#include <math.h>

// GAT: 1024 graphs (B*S), N=256, F=O=64, H=1. One block (4 waves) per graph.
// Round-6: 38.9KB LDS, 4 blocks/CU. Adjacency validity compressed to a
// per-thread 256-bit register mask (8 x u32, all static indexing) DURING
// phase A, interleaved with x@W. Pass 2 carries no adj state -> fits the
// 128-VGPR cap without spilling. One __syncthreads total.

constexpr int NN = 256;
constexpr int FF = 64;
constexpr int OO = 64;

// LDS layout (bytes)
constexpr int OFF_HT  = 0;      // hT[64][256] f16, byte = o*512 + ((2j)^((o&7)<<4))
constexpr int OFF_AL  = 32768;  // al[4 waves][32 rows][40 B] = 5120
constexpr int OFF_AS  = 37888;  // a_s f32[256] = 1024
constexpr int OFF_RED = 38912;  // red f32[4]
constexpr int SMEM_TOTAL = 38928;   // <= 40960 -> 4 blocks/CU

typedef _Float16 half4 __attribute__((ext_vector_type(4)));
typedef float f32x4 __attribute__((ext_vector_type(4)));

__global__ __launch_bounds__(256, 4) void gat_fused(
    const float* __restrict__ x,        // [BS, N, F]
    const int*   __restrict__ adj,      // [BS, N, N]  adj[j][i]!=0 => edge j->i
    const float* __restrict__ W,        // [F, O]
    const float* __restrict__ att_src,  // [O]
    const float* __restrict__ att_dst,  // [O]
    const float* __restrict__ bias,     // [O]
    float* __restrict__ out)            // [BS, N, O]
{
    __shared__ __align__(16) unsigned char smem[SMEM_TOTAL];
    float* as_s  = (float*)(smem + OFF_AS);
    float* red_s = (float*)(smem + OFF_RED);

    const int tid  = threadIdx.x;       // target node i
    const int bs   = blockIdx.x;
    const int lane = tid & 63;
    const int wv   = tid >> 6;

    const float* xg   = x + (size_t)bs * NN * FF;
    const int*   adjg = adj + (size_t)bs * NN * NN;
    float*       outg = out + (size_t)bs * NN * OO;
    const int*   adjcol = adjg + tid;   // column i = tid; lanes -> consecutive cols

    // ---- Phase A: x_i @ W interleaved with adj-column -> 256-bit reg mask ----
    float acc[OO];
    #pragma unroll
    for (int o = 0; o < OO; ++o) acc[o] = 0.f;
    unsigned mbits[8];

    const float4* xv = reinterpret_cast<const float4*>(xg + tid * FF);
    const float4* Wv = reinterpret_cast<const float4*>(W);

    #pragma unroll
    for (int cc = 0; cc < 16; ++cc) {
        // 16 coalesced column loads (rows cc*16..cc*16+15), 256B/wave-instr
        int va[16];
        #pragma unroll
        for (int e = 0; e < 16; ++e)
            va[e] = adjcol[(cc * 16 + e) * NN];

        // one k4 slice of x@W under the loads
        float4 xq = xv[cc];
        float xs[4] = {xq.x, xq.y, xq.z, xq.w};
        #pragma unroll
        for (int kk = 0; kk < 4; ++kk) {
            float xk = xs[kk];
            const float4* wrow = Wv + (cc * 4 + kk) * (OO / 4);
            #pragma unroll
            for (int o4 = 0; o4 < OO / 4; ++o4) {
                float4 w = wrow[o4];   // wave-uniform
                acc[o4 * 4 + 0] = fmaf(xk, w.x, acc[o4 * 4 + 0]);
                acc[o4 * 4 + 1] = fmaf(xk, w.y, acc[o4 * 4 + 1]);
                acc[o4 * 4 + 2] = fmaf(xk, w.z, acc[o4 * 4 + 2]);
                acc[o4 * 4 + 3] = fmaf(xk, w.w, acc[o4 * 4 + 3]);
            }
        }

        // compress to 16 validity bits; self-loop bit OR'd statically
        unsigned mb = ((tid >> 4) == cc) ? (1u << (tid & 15)) : 0u;
        #pragma unroll
        for (int e = 0; e < 16; ++e)
            mb |= (va[e] != 0) ? (1u << e) : 0u;
        if (cc & 1) mbits[cc >> 1] |= (mb << 16);
        else        mbits[cc >> 1]  = mb;

        // keep each batch's VMEM in its batch (ALU may still move freely)
        __builtin_amdgcn_sched_barrier(0x7);
    }

    float as_i = 0.f, ad_i = 0.f;
    {
        const float4* sv = reinterpret_cast<const float4*>(att_src);
        const float4* dv = reinterpret_cast<const float4*>(att_dst);
        #pragma unroll
        for (int o4 = 0; o4 < OO / 4; ++o4) {
            float4 a = sv[o4], d = dv[o4];
            as_i += acc[o4*4+0]*a.x + acc[o4*4+1]*a.y + acc[o4*4+2]*a.z + acc[o4*4+3]*a.w;
            ad_i += acc[o4*4+0]*d.x + acc[o4*4+1]*d.y + acc[o4*4+2]*d.z + acc[o4*4+3]*d.w;
        }
    }
    as_s[tid] = as_i;
    // hT[o][tid] with byte ^= ((o&7)<<4) swizzle
    #pragma unroll
    for (int o = 0; o < OO; ++o) {
        int boff = o * 512 + ((2 * tid) ^ ((o & 7) << 4));
        *(_Float16*)(smem + OFF_HT + boff) = (_Float16)acc[o];
    }

    // Block-wide max of a_s (softmax shift upper bound)
    float vmax = as_i;
    #pragma unroll
    for (int off = 32; off > 0; off >>= 1)
        vmax = fmaxf(vmax, __shfl_xor(vmax, off));
    if (lane == 0) red_s[wv] = vmax;

    __syncthreads();   // the ONLY barrier: hT, as_s, red visible

    const float smax = fmaxf(fmaxf(red_s[0], red_s[1]), fmaxf(red_s[2], red_s[3]));
    float mm = ad_i + smax;
    mm = fmaxf(mm, 0.2f * mm);               // >= leaky(ad_i + as_j) for ALL j
    const float adm = ad_i - mm;             // u  = adm + as_j
    const float c2  = fmaf(0.2f, ad_i, -mm); // v  = fma(0.2, as_j, c2)

    const int r = lane & 15;
    const int g = lane >> 4;

    // alpha buffer addressing (per-wave 32-row region, time-multiplexed)
    const int alw   = OFF_AL + wv * 1280;
    const int wbase = alw + (tid & 31) * 40;     // this thread's write row
    const bool hi   = (tid & 32) != 0;           // lanes 32..63 -> subphase B
    const int afb0  = alw + r * 40 + g * 8;      // A-frag read, rows 0..15
    const int afb1  = alw + (16 + r) * 40 + g * 8;

    // hT B-frag bases (swizzle decomposition)
    const int lo = (g * 8) ^ ((r & 1) << 4);
    const int xh = ((r >> 1) & 3) * 32;
    int bfb[4];
    #pragma unroll
    for (int nc = 0; nc < 4; ++nc) bfb[nc] = OFF_HT + (nc * 16 + r) * 512 + lo;

    f32x4 dacc[4][4];
    #pragma unroll
    for (int c = 0; c < 4; ++c)
        #pragma unroll
        for (int nc = 0; nc < 4; ++nc)
            dacc[c][nc] = (f32x4){0.f, 0.f, 0.f, 0.f};

    float lacc[4] = {0.f, 0.f, 0.f, 0.f};

    // ---- Pass 2: 16 j-tiles of 16, barrier-free (wave-local al) ----
    #pragma unroll
    for (int t = 0; t < 16; ++t) {
        // p (unnormalized alpha, f16) for this thread's row, j = t*16 .. +15
        half4 pq[4];
        #pragma unroll
        for (int q = 0; q < 4; ++q) {
            float4 a4 = *(const float4*)&as_s[t * 16 + q * 4];
            float as4[4] = {a4.x, a4.y, a4.z, a4.w};
            half4 hv;
            #pragma unroll
            for (int e = 0; e < 4; ++e) {
                const int j = t * 16 + q * 4 + e;      // compile-time
                float aj = as4[e];
                float u  = adm + aj;
                float vv = fmaf(0.2f, aj, c2);
                float ev = fmaxf(u, vv);               // leaky(score) - m
                float pf = __expf(ev);
                bool valid = (mbits[j >> 5] >> (j & 31)) & 1u;   // static index
                pf = valid ? pf : 0.f;
                lacc[e] += pf;
                hv[e] = (_Float16)pf;
            }
            pq[q] = hv;
        }

        // B-fragments for this tile (shared by all c-chunks)
        half4 bf[4];
        const int kx = (t * 32) ^ xh;
        #pragma unroll
        for (int nc = 0; nc < 4; ++nc)
            bf[nc] = *(const half4*)(smem + bfb[nc] + kx);

        // subphase A: lanes 0..31 stage rows 0..31
        if (!hi) {
            #pragma unroll
            for (int q = 0; q < 4; ++q)
                *(half4*)(smem + wbase + q * 8) = pq[q];
        }
        asm volatile("" ::: "memory");
        #pragma unroll
        for (int c = 0; c < 2; ++c) {
            half4 af = *(const half4*)(smem + (c ? afb1 : afb0));
            #pragma unroll
            for (int nc = 0; nc < 4; ++nc)
                dacc[c][nc] = __builtin_amdgcn_mfma_f32_16x16x16f16(
                    af, bf[nc], dacc[c][nc], 0, 0, 0);
        }
        asm volatile("" ::: "memory");
        // subphase B: lanes 32..63 reuse the same 32 rows for rows 32..63
        if (hi) {
            #pragma unroll
            for (int q = 0; q < 4; ++q)
                *(half4*)(smem + wbase + q * 8) = pq[q];
        }
        asm volatile("" ::: "memory");
        #pragma unroll
        for (int c = 2; c < 4; ++c) {
            half4 af = *(const half4*)(smem + ((c & 1) ? afb1 : afb0));
            #pragma unroll
            for (int nc = 0; nc < 4; ++nc)
                dacc[c][nc] = __builtin_amdgcn_mfma_f32_16x16x16f16(
                    af, bf[nc], dacc[c][nc], 0, 0, 0);
        }
        asm volatile("" ::: "memory");
    }

    const float l = (lacc[0] + lacc[1]) + (lacc[2] + lacc[3]);
    const float invl = 1.0f / l;     // self-loop term > 0

    // ---- Epilogue: normalize (invl via shfl from owner lane) + bias ----
    float bl[4];
    #pragma unroll
    for (int nc = 0; nc < 4; ++nc) bl[nc] = bias[nc * 16 + r];

    #pragma unroll
    for (int c = 0; c < 4; ++c) {
        #pragma unroll
        for (int q = 0; q < 4; ++q) {
            const int rsel = c * 16 + g * 4 + q;     // owner lane of this row
            float ir = __shfl(invl, rsel, 64);
            const int i_row = wv * 64 + rsel;
            float* orow = outg + (size_t)i_row * OO;
            #pragma unroll
            for (int nc = 0; nc < 4; ++nc)
                orow[nc * 16 + r] = fmaf(dacc[c][nc][q], ir, bl[nc]);
        }
    }
}

extern "C" void kernel_launch(void* const* d_in, const int* in_sizes, int n_in,
                              void* d_out, int out_size, void* d_ws, size_t ws_size,
                              hipStream_t stream) {
    const float* x        = (const float*)d_in[0];
    const int*   adj      = (const int*)  d_in[1];
    const float* W        = (const float*)d_in[2];
    const float* att_src  = (const float*)d_in[3];
    const float* att_dst  = (const float*)d_in[4];
    const float* bias     = (const float*)d_in[5];
    float*       out      = (float*)d_out;

    dim3 grid(1024);
    dim3 block(256);
    hipLaunchKernelGGL(gat_fused, grid, block, 0, stream,
                       x, adj, W, att_src, att_dst, bias, out);
}

// Round 8
// 347.430 us; speedup vs baseline: 1.2323x; 1.2323x over previous
//
#include <hip/hip_runtime.h>
#include <math.h>

// GAT: 1024 graphs (B*S), N=256, F=O=64, H=1. One block (4 waves) per graph.
// Round-8 = round-7 + fix: hT store was missing the wv*128 byte term (all
// waves wrote the same j-quadrant -> uninitialized LDS -> NaN).
// Structure: both GEMMs on MFMA sharing ONE accumulator array (dacc);
// alpha computed directly in A-fragment layout (mask via shfl); no alpha
// LDS; LDS = 34.8KB -> 4 blocks/CU; one __syncthreads.

constexpr int NN = 256;
constexpr int FF = 64;
constexpr int OO = 64;

constexpr int OFF_HT  = 0;      // hT f16: byte = o*512 + ((2j) ^ ((o&7)<<4)), 32768 B
constexpr int OFF_AS  = 32768;  // a_s f32[256]
constexpr int OFF_AD  = 33792;  // a_d f32[256]
constexpr int OFF_RED = 34816;  // red f32[4]
constexpr int SMEM_TOTAL = 34832;   // <= 40960 -> 4 blocks/CU

typedef _Float16 half4 __attribute__((ext_vector_type(4)));
typedef float f32x4 __attribute__((ext_vector_type(4)));

__global__ __launch_bounds__(256, 4) void gat_fused(
    const float* __restrict__ x,        // [BS, N, F]
    const int*   __restrict__ adj,      // [BS, N, N]  adj[j][i]!=0 => edge j->i
    const float* __restrict__ W,        // [F, O]
    const float* __restrict__ att_src,  // [O]
    const float* __restrict__ att_dst,  // [O]
    const float* __restrict__ bias,     // [O]
    float* __restrict__ out)            // [BS, N, O]
{
    __shared__ __align__(16) unsigned char smem[SMEM_TOTAL];
    float* as_s  = (float*)(smem + OFF_AS);
    float* ad_s  = (float*)(smem + OFF_AD);
    float* red_s = (float*)(smem + OFF_RED);

    const int tid  = threadIdx.x;
    const int bs   = blockIdx.x;
    const int lane = tid & 63;
    const int wv   = tid >> 6;
    const int r    = lane & 15;
    const int g    = lane >> 4;
    const int gsh  = g * 4;

    const float* xg     = x + (size_t)bs * NN * FF;
    const int*   adjcol = adj + (size_t)bs * NN * NN + tid;  // column i = tid
    float*       outg   = out + (size_t)bs * NN * OO;

    // Shared accumulator: phase-A h-tiles, then pass-2 out-tiles.
    f32x4 dacc[4][4];
    #pragma unroll
    for (int c = 0; c < 4; ++c)
        #pragma unroll
        for (int nc = 0; nc < 4; ++nc)
            dacc[c][nc] = (f32x4){0.f, 0.f, 0.f, 0.f};

    unsigned mbits[8];

    // adj batch: 16 coalesced column loads -> 16 validity bits (+ self loop)
    #define ADJ_BATCH(cc) do {                                              \
        int va[16];                                                         \
        _Pragma("unroll") for (int e = 0; e < 16; ++e)                      \
            va[e] = adjcol[((cc) * 16 + e) * NN];                           \
        unsigned mb = ((tid >> 4) == (cc)) ? (1u << (tid & 15)) : 0u;       \
        _Pragma("unroll") for (int e = 0; e < 16; ++e)                      \
            mb |= (va[e] != 0) ? (1u << e) : 0u;                            \
        if ((cc) & 1) mbits[(cc) >> 1] |= (mb << 16);                       \
        else          mbits[(cc) >> 1]  = mb;                               \
    } while (0)

    // issue first batches early so their HBM latency hides under x@W
    ADJ_BATCH(0); ADJ_BATCH(1); ADJ_BATCH(2); ADJ_BATCH(3);

    // ---- Phase A: h(rows wv*64..+63) = x @ W via MFMA (f16 in, f32 acc) ----
    #pragma unroll
    for (int kk = 0; kk < 4; ++kk) {
        half4 a[4];
        #pragma unroll
        for (int c = 0; c < 4; ++c) {
            float4 xq = *(const float4*)(xg + (wv * 64 + c * 16 + r) * FF + kk * 16 + gsh);
            a[c] = (half4){(_Float16)xq.x, (_Float16)xq.y, (_Float16)xq.z, (_Float16)xq.w};
        }
        half4 b[4];
        #pragma unroll
        for (int nc = 0; nc < 4; ++nc) {
            #pragma unroll
            for (int q = 0; q < 4; ++q)
                b[nc][q] = (_Float16)W[(kk * 16 + gsh + q) * OO + nc * 16 + r];
        }
        #pragma unroll
        for (int c = 0; c < 4; ++c)
            #pragma unroll
            for (int nc = 0; nc < 4; ++nc)
                dacc[c][nc] = __builtin_amdgcn_mfma_f32_16x16x16f16(
                    a[c], b[nc], dacc[c][nc], 0, 0, 0);
    }

    // remaining adj batches; latency overlaps the score reduction below
    ADJ_BATCH(4);  ADJ_BATCH(5);  ADJ_BATCH(6);  ADJ_BATCH(7);
    ADJ_BATCH(8);  ADJ_BATCH(9);  ADJ_BATCH(10); ADJ_BATCH(11);
    ADJ_BATCH(12); ADJ_BATCH(13); ADJ_BATCH(14); ADJ_BATCH(15);
    #undef ADJ_BATCH

    // ---- Scores + hT store from D-fragments ----
    // D layout: lane (g,r) holds h[row = c*16 + 4g + q][o = nc*16 + r].
    float attS[4], attD[4];
    #pragma unroll
    for (int nc = 0; nc < 4; ++nc) {
        attS[nc] = att_src[nc * 16 + r];
        attD[nc] = att_dst[nc * 16 + r];
    }
    float wmax = -3.0e38f;
    #pragma unroll
    for (int c = 0; c < 4; ++c) {
        float sv[4], dv[4];
        #pragma unroll
        for (int q = 0; q < 4; ++q) {
            float s = dacc[c][0][q] * attS[0] + dacc[c][1][q] * attS[1]
                    + dacc[c][2][q] * attS[2] + dacc[c][3][q] * attS[3];
            float d = dacc[c][0][q] * attD[0] + dacc[c][1][q] * attD[1]
                    + dacc[c][2][q] * attD[2] + dacc[c][3][q] * attD[3];
            #pragma unroll
            for (int off = 1; off < 16; off <<= 1) {
                s += __shfl_xor(s, off);
                d += __shfl_xor(d, off);
            }
            sv[q] = s; dv[q] = d;
            wmax = fmaxf(wmax, s);
        }
        // lanes r<4 write row c*16 + 4g + r (value sv[r])
        float ssel = ((r & 3) == 0) ? sv[0] : ((r & 3) == 1) ? sv[1]
                   : ((r & 3) == 2) ? sv[2] : sv[3];
        float dsel = ((r & 3) == 0) ? dv[0] : ((r & 3) == 1) ? dv[1]
                   : ((r & 3) == 2) ? dv[2] : dv[3];
        if (r < 4) {
            as_s[wv * 64 + c * 16 + gsh + r] = ssel;
            ad_s[wv * 64 + c * 16 + gsh + r] = dsel;
        }
        // hT[o = nc*16+r][j = wv*64 + c*16 + 4g + q], swizzled half4 writes.
        // byte = o*512 + ((2j) ^ ((o&7)<<4)); 2j = wv*128 + 32c + 8g + 2q.
        #pragma unroll
        for (int nc = 0; nc < 4; ++nc) {
            half4 hv = (half4){(_Float16)dacc[c][nc][0], (_Float16)dacc[c][nc][1],
                               (_Float16)dacc[c][nc][2], (_Float16)dacc[c][nc][3]};
            int boff = (nc * 16 + r) * 512
                     + ((wv * 128 + 32 * c + 8 * g) ^ ((r & 7) << 4));
            *(half4*)(smem + OFF_HT + boff) = hv;
        }
    }
    #pragma unroll
    for (int off = 1; off < 64; off <<= 1)
        wmax = fmaxf(wmax, __shfl_xor(wmax, off));
    if (lane == 0) red_s[wv] = wmax;

    __syncthreads();   // the ONLY barrier: hT, as_s, ad_s, red visible

    const float smax = fmaxf(fmaxf(red_s[0], red_s[1]), fmaxf(red_s[2], red_s[3]));

    // per-A-row constants: rows c*16 + r of this wave
    float adm[4], c2[4];
    #pragma unroll
    for (int c = 0; c < 4; ++c) {
        float adr = ad_s[wv * 64 + c * 16 + r];
        float u = adr + smax;
        float mrow = fmaxf(u, 0.2f * u);     // m_row = leaky(ad + smax) >= all scores
        adm[c] = adr - mrow;
        c2[c]  = fmaf(0.2f, adr, -mrow);
    }

    // re-zero the accumulator for pass 2 (same registers)
    #pragma unroll
    for (int c = 0; c < 4; ++c)
        #pragma unroll
        for (int nc = 0; nc < 4; ++nc)
            dacc[c][nc] = (f32x4){0.f, 0.f, 0.f, 0.f};

    // hT B-frag bases (swizzle decomposition: bits 3-4 | bits 5+)
    const int lo = (gsh * 2) ^ ((r & 1) << 4);
    const int xh = ((r >> 1) & 3) * 32;
    int bfb[4];
    #pragma unroll
    for (int nc = 0; nc < 4; ++nc)
        bfb[nc] = OFF_HT + (nc * 16 + r) * 512 + lo;

    float lacc[4] = {0.f, 0.f, 0.f, 0.f};

    // ---- Pass 2: out = alpha @ h; alpha born in A-frag layout ----
    #pragma unroll
    for (int t = 0; t < 16; ++t) {
        float4 as4 = *(const float4*)(smem + OFF_AS + (t * 16 + gsh) * 4);
        float as4a[4] = {as4.x, as4.y, as4.z, as4.w};

        half4 bf[4];
        const int kx = (t * 32) ^ xh;
        #pragma unroll
        for (int nc = 0; nc < 4; ++nc)
            bf[nc] = *(const half4*)(smem + bfb[nc] + kx);

        half4 af[4];
        #pragma unroll
        for (int c = 0; c < 4; ++c) {
            // mask word of row c*16+r, bits j = (t>>1)*32 .. +31 (owner lane shfl)
            unsigned mk = __shfl(mbits[t >> 1], c * 16 + r, 64);
            #pragma unroll
            for (int q = 0; q < 4; ++q) {
                float aj = as4a[q];
                float u  = adm[c] + aj;
                float vv = fmaf(0.2f, aj, c2[c]);
                float pf = __expf(fmaxf(u, vv));
                pf = ((mk >> ((t & 1) * 16 + gsh + q)) & 1u) ? pf : 0.f;
                lacc[c] += pf;
                af[c][q] = (_Float16)pf;
            }
        }
        #pragma unroll
        for (int c = 0; c < 4; ++c)
            #pragma unroll
            for (int nc = 0; nc < 4; ++nc)
                dacc[c][nc] = __builtin_amdgcn_mfma_f32_16x16x16f16(
                    af[c], bf[nc], dacc[c][nc], 0, 0, 0);
    }

    // ---- Epilogue: l per A-row (reduce over g), distribute invl to D rows ----
    float invc[4];
    #pragma unroll
    for (int c = 0; c < 4; ++c) {
        float lr = lacc[c];
        lr += __shfl_xor(lr, 16);
        lr += __shfl_xor(lr, 32);
        invc[c] = 1.0f / lr;        // self-loop term > 0
    }
    float bl[4];
    #pragma unroll
    for (int nc = 0; nc < 4; ++nc) bl[nc] = bias[nc * 16 + r];

    #pragma unroll
    for (int c = 0; c < 4; ++c) {
        #pragma unroll
        for (int q = 0; q < 4; ++q) {
            float ir = __shfl(invc[c], gsh + q, 64);   // lane 4g+q holds row c*16+4g+q
            const int i_row = wv * 64 + c * 16 + gsh + q;
            float* orow = outg + (size_t)i_row * OO;
            #pragma unroll
            for (int nc = 0; nc < 4; ++nc)
                orow[nc * 16 + r] = fmaf(dacc[c][nc][q], ir, bl[nc]);
        }
    }
}

extern "C" void kernel_launch(void* const* d_in, const int* in_sizes, int n_in,
                              void* d_out, int out_size, void* d_ws, size_t ws_size,
                              hipStream_t stream) {
    const float* x        = (const float*)d_in[0];
    const int*   adj      = (const int*)  d_in[1];
    const float* W        = (const float*)d_in[2];
    const float* att_src  = (const float*)d_in[3];
    const float* att_dst  = (const float*)d_in[4];
    const float* bias     = (const float*)d_in[5];
    float*       out      = (float*)d_out;

    dim3 grid(1024);
    dim3 block(256);
    hipLaunchKernelGGL(gat_fused, grid, block, 0, stream,
                       x, adj, W, att_src, att_dst, bias, out);
}

// Round 9
// 124.182 us; speedup vs baseline: 3.4477x; 2.7977x over previous
//
#include <hip/hip_runtime.h>
#include <math.h>

// GAT: 1024 graphs (B*S), N=256, F=O=64, H=1. One block (4 waves) per graph.
// Round-9: round-8 math (MFMA phase A + alpha born in A-frag layout, one
// barrier) with (a) launch_bounds(256,3) so nothing spills, and (b) adj read
// via int4 row loads (1KB/wave-instr, 8-deep) + ballot bit-transpose:
// v_cndmask scatters ballot bit l to lane l; lane l owns columns 4l..4l+3;
// cross-wave exchange through mrow LDS (each wave fills words 2wv,2wv+1 of
// every target row). Pass 2 identical to round 8 (passed, absmax 0.0039).

constexpr int NN = 256;
constexpr int FF = 64;
constexpr int OO = 64;

constexpr int OFF_HT   = 0;      // hT f16: byte = o*512 + ((2j) ^ ((o&7)<<4)); 32768 B
constexpr int OFF_MROW = 32768;  // mrow[256 rows][40 B] (8 words used) = 10240 B
constexpr int OFF_AS   = 43008;  // a_s f32[256]
constexpr int OFF_AD   = 44032;  // a_d f32[256]
constexpr int OFF_RED  = 45056;  // red f32[4]
constexpr int SMEM_TOTAL = 45072;    // <= 54613 -> 3 blocks/CU

typedef _Float16 half4 __attribute__((ext_vector_type(4)));
typedef float f32x4 __attribute__((ext_vector_type(4)));

__global__ __launch_bounds__(256, 3) void gat_fused(
    const float* __restrict__ x,        // [BS, N, F]
    const int*   __restrict__ adj,      // [BS, N, N]  adj[j][i]!=0 => edge j->i
    const float* __restrict__ W,        // [F, O]
    const float* __restrict__ att_src,  // [O]
    const float* __restrict__ att_dst,  // [O]
    const float* __restrict__ bias,     // [O]
    float* __restrict__ out)            // [BS, N, O]
{
    __shared__ __align__(16) unsigned char smem[SMEM_TOTAL];
    float* as_s  = (float*)(smem + OFF_AS);
    float* ad_s  = (float*)(smem + OFF_AD);
    float* red_s = (float*)(smem + OFF_RED);

    const int tid  = threadIdx.x;
    const int bs   = blockIdx.x;
    const int lane = tid & 63;
    const int wv   = tid >> 6;
    const int r    = lane & 15;
    const int g    = lane >> 4;
    const int gsh  = g * 4;

    const float* xg   = x + (size_t)bs * NN * FF;
    const int4*  adjv = reinterpret_cast<const int4*>(adj + (size_t)bs * NN * NN);
    float*       outg = out + (size_t)bs * NN * OO;

    // Shared accumulator: phase-A h-tiles, then pass-2 out-tiles.
    f32x4 dacc[4][4];
    #pragma unroll
    for (int c = 0; c < 4; ++c)
        #pragma unroll
        for (int nc = 0; nc < 4; ++nc)
            dacc[c][nc] = (f32x4){0.f, 0.f, 0.f, 0.f};

    // validity words for this lane's 4 owned columns (4*lane+q), rows of wave wv
    unsigned wcol[4][2] = {{0u,0u},{0u,0u},{0u,0u},{0u,0u}};

    // ---- Phase A: adj staging (int4+ballot transpose) interleaved with x@W MFMA ----
    #pragma unroll
    for (int ch = 0; ch < 8; ++ch) {
        // 8 fat row loads in flight: rows j = wv*64 + ch*8 + k, cols 4*lane..+3
        int4 v[8];
        #pragma unroll
        for (int k = 0; k < 8; ++k)
            v[k] = adjv[(wv * 64 + ch * 8 + k) * 64 + lane];

        // one x@W kk-slice under every other chunk's loads
        if ((ch & 1) == 0) {
            const int kk = ch >> 1;
            half4 a[4];
            #pragma unroll
            for (int c = 0; c < 4; ++c) {
                float4 xq = *(const float4*)(xg + (wv * 64 + c * 16 + r) * FF + kk * 16 + gsh);
                a[c] = (half4){(_Float16)xq.x, (_Float16)xq.y, (_Float16)xq.z, (_Float16)xq.w};
            }
            half4 b[4];
            #pragma unroll
            for (int nc = 0; nc < 4; ++nc) {
                #pragma unroll
                for (int q = 0; q < 4; ++q)
                    b[nc][q] = (_Float16)W[(kk * 16 + gsh + q) * OO + nc * 16 + r];
            }
            #pragma unroll
            for (int c = 0; c < 4; ++c)
                #pragma unroll
                for (int nc = 0; nc < 4; ++nc)
                    dacc[c][nc] = __builtin_amdgcn_mfma_f32_16x16x16f16(
                        a[c], b[nc], dacc[c][nc], 0, 0, 0);
        }

        // ballot transpose: 4 ballots/row; cndmask scatters bit l -> lane l
        #pragma unroll
        for (int k = 0; k < 8; ++k) {
            const int it = ch * 8 + k;          // row index within wave: compile-time
            const int wd = it >> 5;             // target word (compile-time)
            const int sh = it & 31;             // bit position (compile-time)
            unsigned long long b0 = __ballot(v[k].x != 0);
            unsigned long long b1 = __ballot(v[k].y != 0);
            unsigned long long b2 = __ballot(v[k].z != 0);
            unsigned long long b3 = __ballot(v[k].w != 0);
            unsigned t0, t1, t2, t3;
            asm("v_cndmask_b32 %0, 0, 1, %1" : "=v"(t0) : "s"(b0));
            asm("v_cndmask_b32 %0, 0, 1, %1" : "=v"(t1) : "s"(b1));
            asm("v_cndmask_b32 %0, 0, 1, %1" : "=v"(t2) : "s"(b2));
            asm("v_cndmask_b32 %0, 0, 1, %1" : "=v"(t3) : "s"(b3));
            wcol[0][wd] |= t0 << sh;
            wcol[1][wd] |= t1 << sh;
            wcol[2][wd] |= t2 << sh;
            wcol[3][wd] |= t3 << sh;
        }
    }

    // publish: column c = 4*lane+q gets words [2wv, 2wv+1] from this wave
    #pragma unroll
    for (int q = 0; q < 4; ++q) {
        uint2 wq; wq.x = wcol[q][0]; wq.y = wcol[q][1];
        *(uint2*)(smem + OFF_MROW + (lane * 4 + q) * 40 + wv * 8) = wq;
    }

    // ---- Scores + hT store from D-fragments ----
    // D layout: lane (g,r) holds h[row = c*16 + 4g + q][o = nc*16 + r].
    float attS[4], attD[4];
    #pragma unroll
    for (int nc = 0; nc < 4; ++nc) {
        attS[nc] = att_src[nc * 16 + r];
        attD[nc] = att_dst[nc * 16 + r];
    }
    float wmax = -3.0e38f;
    #pragma unroll
    for (int c = 0; c < 4; ++c) {
        float sv[4], dv[4];
        #pragma unroll
        for (int q = 0; q < 4; ++q) {
            float s = dacc[c][0][q] * attS[0] + dacc[c][1][q] * attS[1]
                    + dacc[c][2][q] * attS[2] + dacc[c][3][q] * attS[3];
            float d = dacc[c][0][q] * attD[0] + dacc[c][1][q] * attD[1]
                    + dacc[c][2][q] * attD[2] + dacc[c][3][q] * attD[3];
            #pragma unroll
            for (int off = 1; off < 16; off <<= 1) {
                s += __shfl_xor(s, off);
                d += __shfl_xor(d, off);
            }
            sv[q] = s; dv[q] = d;
            wmax = fmaxf(wmax, s);
        }
        float ssel = ((r & 3) == 0) ? sv[0] : ((r & 3) == 1) ? sv[1]
                   : ((r & 3) == 2) ? sv[2] : sv[3];
        float dsel = ((r & 3) == 0) ? dv[0] : ((r & 3) == 1) ? dv[1]
                   : ((r & 3) == 2) ? dv[2] : dv[3];
        if (r < 4) {
            as_s[wv * 64 + c * 16 + gsh + r] = ssel;
            ad_s[wv * 64 + c * 16 + gsh + r] = dsel;
        }
        // hT[o = nc*16+r][j = wv*64 + c*16 + 4g + q]; 2j = wv*128+32c+8g+2q
        #pragma unroll
        for (int nc = 0; nc < 4; ++nc) {
            half4 hv = (half4){(_Float16)dacc[c][nc][0], (_Float16)dacc[c][nc][1],
                               (_Float16)dacc[c][nc][2], (_Float16)dacc[c][nc][3]};
            int boff = (nc * 16 + r) * 512
                     + ((wv * 128 + 32 * c + 8 * g) ^ ((r & 7) << 4));
            *(half4*)(smem + OFF_HT + boff) = hv;
        }
    }
    #pragma unroll
    for (int off = 1; off < 64; off <<= 1)
        wmax = fmaxf(wmax, __shfl_xor(wmax, off));
    if (lane == 0) red_s[wv] = wmax;

    __syncthreads();   // the ONLY barrier: hT, mrow, as_s, ad_s, red visible

    // readback own row's mask words (+ self-loop, static indices)
    unsigned mbits[8];
    {
        uint2 m01 = *(const uint2*)(smem + OFF_MROW + tid * 40 + 0);
        uint2 m23 = *(const uint2*)(smem + OFF_MROW + tid * 40 + 8);
        uint2 m45 = *(const uint2*)(smem + OFF_MROW + tid * 40 + 16);
        uint2 m67 = *(const uint2*)(smem + OFF_MROW + tid * 40 + 24);
        mbits[0] = m01.x; mbits[1] = m01.y; mbits[2] = m23.x; mbits[3] = m23.y;
        mbits[4] = m45.x; mbits[5] = m45.y; mbits[6] = m67.x; mbits[7] = m67.y;
        #pragma unroll
        for (int k = 0; k < 8; ++k)
            if ((tid >> 5) == k) mbits[k] |= 1u << (tid & 31);
    }

    const float smax = fmaxf(fmaxf(red_s[0], red_s[1]), fmaxf(red_s[2], red_s[3]));

    // per-A-row constants: rows c*16 + r of this wave
    float adm[4], c2[4];
    #pragma unroll
    for (int c = 0; c < 4; ++c) {
        float adr = ad_s[wv * 64 + c * 16 + r];
        float u = adr + smax;
        float mrow = fmaxf(u, 0.2f * u);     // m_row >= all scores of this row
        adm[c] = adr - mrow;
        c2[c]  = fmaf(0.2f, adr, -mrow);
    }

    // re-zero the accumulator for pass 2 (same registers)
    #pragma unroll
    for (int c = 0; c < 4; ++c)
        #pragma unroll
        for (int nc = 0; nc < 4; ++nc)
            dacc[c][nc] = (f32x4){0.f, 0.f, 0.f, 0.f};

    // hT B-frag bases (swizzle decomposition: bits 3-4 | bits 5+)
    const int lo = (gsh * 2) ^ ((r & 1) << 4);
    const int xh = ((r >> 1) & 3) * 32;
    int bfb[4];
    #pragma unroll
    for (int nc = 0; nc < 4; ++nc)
        bfb[nc] = OFF_HT + (nc * 16 + r) * 512 + lo;

    float lacc[4] = {0.f, 0.f, 0.f, 0.f};

    // ---- Pass 2: out = alpha @ h; alpha born in A-frag layout ----
    #pragma unroll
    for (int t = 0; t < 16; ++t) {
        float4 as4 = *(const float4*)(smem + OFF_AS + (t * 16 + gsh) * 4);
        float as4a[4] = {as4.x, as4.y, as4.z, as4.w};

        half4 bf[4];
        const int kx = (t * 32) ^ xh;
        #pragma unroll
        for (int nc = 0; nc < 4; ++nc)
            bf[nc] = *(const half4*)(smem + bfb[nc] + kx);

        half4 af[4];
        #pragma unroll
        for (int c = 0; c < 4; ++c) {
            // mask word of row c*16+r, bits j = (t>>1)*32 .. +31
            unsigned mk = __shfl(mbits[t >> 1], c * 16 + r, 64);
            #pragma unroll
            for (int q = 0; q < 4; ++q) {
                float aj = as4a[q];
                float u  = adm[c] + aj;
                float vv = fmaf(0.2f, aj, c2[c]);
                float pf = __expf(fmaxf(u, vv));
                pf = ((mk >> ((t & 1) * 16 + gsh + q)) & 1u) ? pf : 0.f;
                lacc[c] += pf;
                af[c][q] = (_Float16)pf;
            }
        }
        #pragma unroll
        for (int c = 0; c < 4; ++c)
            #pragma unroll
            for (int nc = 0; nc < 4; ++nc)
                dacc[c][nc] = __builtin_amdgcn_mfma_f32_16x16x16f16(
                    af[c], bf[nc], dacc[c][nc], 0, 0, 0);
    }

    // ---- Epilogue: l per A-row (reduce over g), distribute invl to D rows ----
    float invc[4];
    #pragma unroll
    for (int c = 0; c < 4; ++c) {
        float lr = lacc[c];
        lr += __shfl_xor(lr, 16);
        lr += __shfl_xor(lr, 32);
        invc[c] = 1.0f / lr;        // self-loop term > 0
    }
    float bl[4];
    #pragma unroll
    for (int nc = 0; nc < 4; ++nc) bl[nc] = bias[nc * 16 + r];

    #pragma unroll
    for (int c = 0; c < 4; ++c) {
        #pragma unroll
        for (int q = 0; q < 4; ++q) {
            float ir = __shfl(invc[c], gsh + q, 64);   // lane 4g+q holds row c*16+4g+q
            const int i_row = wv * 64 + c * 16 + gsh + q;
            float* orow = outg + (size_t)i_row * OO;
            #pragma unroll
            for (int nc = 0; nc < 4; ++nc)
                orow[nc * 16 + r] = fmaf(dacc[c][nc][q], ir, bl[nc]);
        }
    }
}

extern "C" void kernel_launch(void* const* d_in, const int* in_sizes, int n_in,
                              void* d_out, int out_size, void* d_ws, size_t ws_size,
                              hipStream_t stream) {
    const float* x        = (const float*)d_in[0];
    const int*   adj      = (const int*)  d_in[1];
    const float* W        = (const float*)d_in[2];
    const float* att_src  = (const float*)d_in[3];
    const float* att_dst  = (const float*)d_in[4];
    const float* bias     = (const float*)d_in[5];
    float*       out      = (float*)d_out;

    dim3 grid(1024);
    dim3 block(256);
    hipLaunchKernelGGL(gat_fused, grid, block, 0, stream,
                       x, adj, W, att_src, att_dst, bias, out);
}